// Round 6
// baseline (541.496 us; speedup 1.0000x reference)
//
#include <hip/hip_runtime.h>
#include <math.h>

#define B_      2
#define S_      2048
#define HIDDEN_ 2048
#define HEADS_  16
#define QLORA_  1024
#define KVLORA_ 512
#define NOPE_   128
#define ROPE_   64
#define QHEAD_  192
#define VHEAD_  128

typedef __attribute__((ext_vector_type(8))) short bf16x8;
typedef __attribute__((ext_vector_type(4))) float f32x4;

#define AS1 __attribute__((address_space(1)))
#define AS3 __attribute__((address_space(3)))

static __device__ __forceinline__ unsigned short f2bf(float f) {
  unsigned u = __builtin_bit_cast(unsigned, f);
  u += 0x7fffu + ((u >> 16) & 1u);  // RTNE
  return (unsigned short)(u >> 16);
}
static __device__ __forceinline__ float b2f(unsigned short s) {
  unsigned u = ((unsigned)s) << 16;
  return __builtin_bit_cast(float, u);
}

// ---------------------------------------------------------------------------
// bf16 MFMA GEMM (m97 structure): C[M,N] = A[M,K] @ Bt[N,K]^T
// Tile 128x128, BK=32, 4 waves (2x2 of 64x64), 4x4 MFMA acc/wave.
// ---------------------------------------------------------------------------
template <typename TC>
__global__ __launch_bounds__(256) void gemm_bt(
    const unsigned short* __restrict__ A, int lda,   // [M][K] bf16
    const unsigned short* __restrict__ Bt, int ldb,  // [N][K] bf16
    TC* __restrict__ C, int ldc, int K) {
  __shared__ __align__(16) unsigned short As[128][32];
  __shared__ __align__(16) unsigned short Bs[128][32];

  const int tid = threadIdx.x;
  const int lane = tid & 63, wv = tid >> 6;
  const int m = lane & 15, quad = lane >> 4;
  const int wm = wv >> 1, wn = wv & 1;
  const int bm = blockIdx.y * 128, bn = blockIdx.x * 128;

  const int srow = lane >> 2;
  const int gchunk = (lane & 3) ^ ((lane >> 3) & 3);
  const int koff = (quad ^ ((m >> 1) & 3)) * 8;

  f32x4 acc[4][4] = {};

  const unsigned short* Ab = A + (size_t)bm * lda;
  const unsigned short* Bb = Bt + (size_t)bn * ldb;

  for (int k0 = 0; k0 < K; k0 += 32) {
    __syncthreads();
#pragma unroll
    for (int j = 0; j < 2; ++j) {
      const int t = wv * 2 + j;
      const int r = t * 16 + srow;
      __builtin_amdgcn_global_load_lds(
          (const AS1 unsigned int*)(Ab + (size_t)r * lda + k0 + gchunk * 8),
          (AS3 unsigned int*)(&As[0][0] + t * 512), 16, 0, 0);
      __builtin_amdgcn_global_load_lds(
          (const AS1 unsigned int*)(Bb + (size_t)r * ldb + k0 + gchunk * 8),
          (AS3 unsigned int*)(&Bs[0][0] + t * 512), 16, 0, 0);
    }
    __syncthreads();

    bf16x8 af[4], bfr[4];
#pragma unroll
    for (int mt = 0; mt < 4; ++mt)
      af[mt] = *(const bf16x8*)&As[wm * 64 + mt * 16 + m][koff];
#pragma unroll
    for (int nt = 0; nt < 4; ++nt)
      bfr[nt] = *(const bf16x8*)&Bs[wn * 64 + nt * 16 + m][koff];
#pragma unroll
    for (int mt = 0; mt < 4; ++mt)
#pragma unroll
      for (int nt = 0; nt < 4; ++nt)
        acc[mt][nt] = __builtin_amdgcn_mfma_f32_16x16x32_bf16(af[mt], bfr[nt], acc[mt][nt], 0, 0, 0);
  }

#pragma unroll
  for (int mt = 0; mt < 4; ++mt) {
#pragma unroll
    for (int reg = 0; reg < 4; ++reg) {
      const size_t row = (size_t)bm + wm * 64 + mt * 16 + quad * 4 + reg;
#pragma unroll
      for (int nt = 0; nt < 4; ++nt) {
        const size_t col = (size_t)bn + wn * 64 + nt * 16 + m;
        float v = acc[mt][nt][reg];
        if constexpr (sizeof(TC) == 4) {
          ((float*)C)[row * ldc + col] = v;
        } else {
          ((unsigned short*)C)[row * ldc + col] = f2bf(v);
        }
      }
    }
  }
}

// ---------------------------------------------------------------------------
// kv_up GEMM with fused scatter-epilogue:
//   C[s][c] with h=c>>8, cc=c&255:
//     cc<128  -> knb[s][h*128+cc]          (K-nope, compact)
//     cc>=128 -> vtb[(b*16+h)*128+(cc-128)][seq]  (V, pre-transposed)
// Replaces the separate pack_vt kernel.
// ---------------------------------------------------------------------------
__global__ __launch_bounds__(256) void gemm_kv(
    const unsigned short* __restrict__ A, int lda,   // ckv [4096][lda], K=512
    const unsigned short* __restrict__ Bt, int ldb,  // Wkv_up^T [4096][512]
    unsigned short* __restrict__ knb,                // [4096][2048]
    unsigned short* __restrict__ vtb,                // [32*128][2048]
    int K) {
  __shared__ __align__(16) unsigned short As[128][32];
  __shared__ __align__(16) unsigned short Bs[128][32];

  const int tid = threadIdx.x;
  const int lane = tid & 63, wv = tid >> 6;
  const int m = lane & 15, quad = lane >> 4;
  const int wm = wv >> 1, wn = wv & 1;
  const int bm = blockIdx.y * 128, bn = blockIdx.x * 128;

  const int srow = lane >> 2;
  const int gchunk = (lane & 3) ^ ((lane >> 3) & 3);
  const int koff = (quad ^ ((m >> 1) & 3)) * 8;

  f32x4 acc[4][4] = {};

  const unsigned short* Ab = A + (size_t)bm * lda;
  const unsigned short* Bb = Bt + (size_t)bn * ldb;

  for (int k0 = 0; k0 < K; k0 += 32) {
    __syncthreads();
#pragma unroll
    for (int j = 0; j < 2; ++j) {
      const int t = wv * 2 + j;
      const int r = t * 16 + srow;
      __builtin_amdgcn_global_load_lds(
          (const AS1 unsigned int*)(Ab + (size_t)r * lda + k0 + gchunk * 8),
          (AS3 unsigned int*)(&As[0][0] + t * 512), 16, 0, 0);
      __builtin_amdgcn_global_load_lds(
          (const AS1 unsigned int*)(Bb + (size_t)r * ldb + k0 + gchunk * 8),
          (AS3 unsigned int*)(&Bs[0][0] + t * 512), 16, 0, 0);
    }
    __syncthreads();

    bf16x8 af[4], bfr[4];
#pragma unroll
    for (int mt = 0; mt < 4; ++mt)
      af[mt] = *(const bf16x8*)&As[wm * 64 + mt * 16 + m][koff];
#pragma unroll
    for (int nt = 0; nt < 4; ++nt)
      bfr[nt] = *(const bf16x8*)&Bs[wn * 64 + nt * 16 + m][koff];
#pragma unroll
    for (int mt = 0; mt < 4; ++mt)
#pragma unroll
      for (int nt = 0; nt < 4; ++nt)
        acc[mt][nt] = __builtin_amdgcn_mfma_f32_16x16x32_bf16(af[mt], bfr[nt], acc[mt][nt], 0, 0, 0);
  }

#pragma unroll
  for (int mt = 0; mt < 4; ++mt) {
#pragma unroll
    for (int reg = 0; reg < 4; ++reg) {
      const int s = bm + wm * 64 + mt * 16 + quad * 4 + reg;
      const int bb = s >> 11, seq = s & 2047;
#pragma unroll
      for (int nt = 0; nt < 4; ++nt) {
        const int c = bn + wn * 64 + nt * 16 + m;
        const int h = c >> 8, cc = c & 255;
        unsigned short v = f2bf(acc[mt][nt][reg]);
        if (cc < 128)
          knb[(size_t)s * 2048 + h * 128 + cc] = v;
        else
          vtb[((size_t)(bb * 16 + h) * 128 + (cc - 128)) * 2048 + seq] = v;
      }
    }
  }
}

// ---------------------------------------------------------------------------
// Weight transpose+cast: W fp32 [K][N] -> Wt bf16 [Npad][K] (zero-pad n>=N).
// ---------------------------------------------------------------------------
__global__ __launch_bounds__(256) void transpose_cast(
    const float* __restrict__ W, int K, int N,
    unsigned short* __restrict__ Wt) {
  __shared__ unsigned short t[32][33];
  const int k0 = blockIdx.x * 32, n0 = blockIdx.y * 32;
  const int tx = threadIdx.x, ty = threadIdx.y;
#pragma unroll
  for (int i = 0; i < 4; ++i) {
    int k = k0 + ty + i * 8, n = n0 + tx;
    float v = (n < N) ? W[(size_t)k * N + n] : 0.0f;
    t[ty + i * 8][tx] = f2bf(v);
  }
  __syncthreads();
#pragma unroll
  for (int i = 0; i < 4; ++i) {
    int n = ty + i * 8;
    Wt[(size_t)(n0 + n) * K + k0 + tx] = t[tx][n];
  }
}

__global__ void cast_bf16(const float* __restrict__ src,
                          unsigned short* __restrict__ dst, int n4) {
  int i = blockIdx.x * blockDim.x + threadIdx.x;
  if (i >= n4) return;
  float4 v = ((const float4*)src)[i];
  ushort4 o;
  o.x = f2bf(v.x); o.y = f2bf(v.y); o.z = f2bf(v.z); o.w = f2bf(v.w);
  ((ushort4*)dst)[i] = o;
}

// ---------------------------------------------------------------------------
// RoPE: qb bf16 in-place; k_rope from qckvb [bs][1664] cols 1536..1599 -> krb.
// ---------------------------------------------------------------------------
__global__ void rope_kernel(unsigned short* __restrict__ qb,
                            const unsigned short* __restrict__ qckvb,
                            unsigned short* __restrict__ krb,
                            const int* __restrict__ position) {
  int idx = blockIdx.x * blockDim.x + threadIdx.x;
  const int total = B_ * S_ * 17 * 32;
  if (idx >= total) return;
  int i = idx & 31;
  int u = idx >> 5;
  int h = u % 17;
  int bs = u / 17;
  int s = bs % S_;
  float pos = (float)position[s];
  float inv_freq = powf(10000.0f, -(float)i / 32.0f);
  float ang = pos * inv_freq;
  float c = cosf(ang), sn = sinf(ang);
  if (h < 16) {
    unsigned short* t = qb + (size_t)bs * 3072 + h * QHEAD_ + NOPE_;
    float t1 = b2f(t[i]), t2 = b2f(t[i + 32]);
    t[i]      = f2bf(t1 * c - t2 * sn);
    t[i + 32] = f2bf(t2 * c + t1 * sn);
  } else {
    const unsigned short* t = qckvb + (size_t)bs * 1664 + 1024 + 512;
    float t1 = b2f(t[i]), t2 = b2f(t[i + 32]);
    krb[(size_t)bs * 64 + i]      = f2bf(t1 * c - t2 * sn);
    krb[(size_t)bs * 64 + i + 32] = f2bf(t2 * c + t1 * sn);
  }
}

// ---------------------------------------------------------------------------
// Flash attention, bf16 MFMA, max-free softmax, Q-tile 128 (4 waves x 32 rows).
// R6: all staging via global_load_lds (width=16) with XOR slot swizzles so
// compute-side ds_read_b128 is 2-way max; Ps shrunk to per-ch [32][40].
// LDS 51.2 KB. Grid (S/128, HEADS, B).
// ---------------------------------------------------------------------------
__global__ __launch_bounds__(256) void attn_mfma(
    const unsigned short* __restrict__ qb,   // [bs][3072] bf16, rope applied
    const unsigned short* __restrict__ knb,  // [bs][2048] bf16 k_nope compact
    const unsigned short* __restrict__ krb,  // [bs][64] bf16 roped k_rope
    const unsigned short* __restrict__ vtb,  // [(b*16+h)*128+d][2048] bf16
    unsigned short* __restrict__ aob) {      // [bs][2048] bf16
  __shared__ __align__(16) unsigned short Ksn[64 * 128];  // key*128 + slot*8
  __shared__ __align__(16) unsigned short Ksr[64 * 64];   // key*64  + slot*8
  __shared__ __align__(16) unsigned short Vt[128 * 64];   // d*64    + slot*8
  __shared__ __align__(16) unsigned short Ps[4][32][40];  // per-wave, per-ch

  const int qt = blockIdx.x, h = blockIdx.y, b = blockIdx.z;
  const int tid = threadIdx.x;
  const int lane = tid & 63, wv = tid >> 6;
  const int m = lane & 15, quad = lane >> 4;
  const int bS = b * S_;
  const int bh = b * 16 + h;
  const float scale = 0.072168783649f;  // 1/sqrt(192)

  // Q A-fragments for 2 M-tiles (32 q-rows per wave), loaded once
  bf16x8 qf[2][6];
#pragma unroll
  for (int mt2 = 0; mt2 < 2; ++mt2) {
    const unsigned short* qptr =
        qb + (size_t)(bS + qt * 128 + wv * 32 + mt2 * 16 + m) * 3072 + h * QHEAD_ + quad * 8;
#pragma unroll
    for (int c = 0; c < 6; ++c) qf[mt2][c] = *(const bf16x8*)(qptr + c * 32);
  }

  const bf16x8 vone = {0x3F80, 0x3F80, 0x3F80, 0x3F80, 0x3F80, 0x3F80, 0x3F80, 0x3F80};

  f32x4 o[2][8] = {};
  f32x4 o9[2] = {};

  for (int kt = 0; kt < S_; kt += 64) {
    __syncthreads();  // previous tile's LDS readers done
    // --- async staging (global_load_lds): lane writes lds_base + lane*16B ---
    // K-nope: 64 keys x 256B; instr covers 4 keys; slot = chunk ^ (key&15)
#pragma unroll
    for (int j = 0; j < 4; ++j) {
      int i = wv * 4 + j;
      int key = i * 4 + (lane >> 4);
      int cc = (lane & 15) ^ (key & 15);
      __builtin_amdgcn_global_load_lds(
          (const AS1 unsigned int*)(knb + (size_t)(bS + kt + key) * 2048 + h * 128 + cc * 8),
          (AS3 unsigned int*)(Ksn + i * 512), 16, 0, 0);
    }
    // K-rope: 64 keys x 128B; instr covers 8 keys; slot = chunk ^ (key&7)
#pragma unroll
    for (int j = 0; j < 2; ++j) {
      int i = wv * 2 + j;
      int key = i * 8 + (lane >> 3);
      int cc = (lane & 7) ^ (key & 7);
      __builtin_amdgcn_global_load_lds(
          (const AS1 unsigned int*)(krb + (size_t)(bS + kt + key) * 64 + cc * 8),
          (AS3 unsigned int*)(Ksr + i * 512), 16, 0, 0);
    }
    // Vt: 128 d-rows x 128B; instr covers 8 rows; slot = chunk ^ (d&7)
#pragma unroll
    for (int j = 0; j < 4; ++j) {
      int i = wv * 4 + j;
      int d = i * 8 + (lane >> 3);
      int cc = (lane & 7) ^ (d & 7);
      __builtin_amdgcn_global_load_lds(
          (const AS1 unsigned int*)(vtb + ((size_t)bh * 128 + d) * 2048 + kt + cc * 8),
          (AS3 unsigned int*)(Vt + i * 512), 16, 0, 0);
    }
    __syncthreads();  // vmcnt(0) drain -> tiles complete

    // --- QK^T: each K-frag read feeds both M-tiles ---
    f32x4 sc[2][4] = {};
#pragma unroll
    for (int c = 0; c < 4; ++c) {  // nope chunks
#pragma unroll
      for (int f = 0; f < 4; ++f) {
        int slot = (c * 4 + quad) ^ m;
        bf16x8 kf = *(const bf16x8*)&Ksn[(f * 16 + m) * 128 + slot * 8];
        sc[0][f] = __builtin_amdgcn_mfma_f32_16x16x32_bf16(qf[0][c], kf, sc[0][f], 0, 0, 0);
        sc[1][f] = __builtin_amdgcn_mfma_f32_16x16x32_bf16(qf[1][c], kf, sc[1][f], 0, 0, 0);
      }
    }
#pragma unroll
    for (int c2 = 0; c2 < 2; ++c2) {  // rope chunks
#pragma unroll
      for (int f = 0; f < 4; ++f) {
        int slot = (c2 * 4 + quad) ^ (m & 7);
        bf16x8 kf = *(const bf16x8*)&Ksr[(f * 16 + m) * 64 + slot * 8];
        sc[0][f] = __builtin_amdgcn_mfma_f32_16x16x32_bf16(qf[0][4 + c2], kf, sc[0][f], 0, 0, 0);
        sc[1][f] = __builtin_amdgcn_mfma_f32_16x16x32_bf16(qf[1][4 + c2], kf, sc[1][f], 0, 0, 0);
      }
    }

    // --- softmax (max-free) + PV, interleaved per 32-key half ---
#pragma unroll
    for (int ch = 0; ch < 2; ++ch) {
#pragma unroll
      for (int mt2 = 0; mt2 < 2; ++mt2)
#pragma unroll
        for (int g = 0; g < 2; ++g) {
          int f = ch * 2 + g;
#pragma unroll
          for (int r = 0; r < 4; ++r)
            Ps[wv][mt2 * 16 + quad * 4 + r][g * 16 + m] = f2bf(__expf(sc[mt2][f][r] * scale));
        }
      bf16x8 pf0 = *(const bf16x8*)&Ps[wv][m][quad * 8];
      bf16x8 pf1 = *(const bf16x8*)&Ps[wv][16 + m][quad * 8];
      int vslot = (ch * 4 + quad) ^ (m & 7);
#pragma unroll
      for (int nt = 0; nt < 8; ++nt) {
        bf16x8 vf = *(const bf16x8*)&Vt[(nt * 16 + m) * 64 + vslot * 8];
        o[0][nt] = __builtin_amdgcn_mfma_f32_16x16x32_bf16(pf0, vf, o[0][nt], 0, 0, 0);
        o[1][nt] = __builtin_amdgcn_mfma_f32_16x16x32_bf16(pf1, vf, o[1][nt], 0, 0, 0);
      }
      o9[0] = __builtin_amdgcn_mfma_f32_16x16x32_bf16(pf0, vone, o9[0], 0, 0, 0);
      o9[1] = __builtin_amdgcn_mfma_f32_16x16x32_bf16(pf1, vone, o9[1], 0, 0, 0);
    }
  }

#pragma unroll
  for (int mt2 = 0; mt2 < 2; ++mt2) {
#pragma unroll
    for (int r = 0; r < 4; ++r) {
      float inv = 1.0f / o9[mt2][r];
      size_t row = (size_t)(bS + qt * 128 + wv * 32 + mt2 * 16 + quad * 4 + r);
#pragma unroll
      for (int nt = 0; nt < 8; ++nt)
        aob[row * 2048 + h * VHEAD_ + nt * 16 + m] = f2bf(o[mt2][nt][r] * inv);
    }
  }
}

// ---------------------------------------------------------------------------
extern "C" void kernel_launch(void* const* d_in, const int* in_sizes, int n_in,
                              void* d_out, int out_size, void* d_ws, size_t ws_size,
                              hipStream_t stream) {
  const float* x        = (const float*)d_in[0];
  const int*   position = (const int*)d_in[1];
  const float* Wq_down  = (const float*)d_in[2];  // [2048,1024]
  const float* Wq_up    = (const float*)d_in[3];  // [1024,3072]
  const float* Wkv_down = (const float*)d_in[4];  // [2048,576]
  const float* Wkv_up   = (const float*)d_in[5];  // [512,4096]
  const float* Wout     = (const float*)d_in[6];  // [2048,2048]
  float* out = (float*)d_out;

  char* w = (char*)d_ws;
  size_t off = 0;
  auto alloc = [&](size_t bytes) { char* p = w + off; off += (bytes + 255) & ~size_t(255); return p; };
  unsigned short* xb      = (unsigned short*)alloc(4096ull * 2048 * 2);
  unsigned short* qckvb   = (unsigned short*)alloc(4096ull * 1664 * 2);  // [qdown | ckv(640)]
  unsigned short* qb      = (unsigned short*)alloc(4096ull * 3072 * 2);
  unsigned short* knb     = (unsigned short*)alloc(4096ull * 2048 * 2);  // k_nope compact
  unsigned short* vtb     = (unsigned short*)alloc(32ull * 128 * 2048 * 2);
  unsigned short* krb     = (unsigned short*)alloc(4096ull * 64 * 2);
  unsigned short* aob     = (unsigned short*)alloc(4096ull * 2048 * 2);
  unsigned short* Wqdkv_t = (unsigned short*)alloc(1664ull * 2048 * 2);  // [Wqd^T | Wkvd^T(640)]
  unsigned short* Wqu_t   = (unsigned short*)alloc(3072ull * 1024 * 2);
  unsigned short* Wkvu_t  = (unsigned short*)alloc(4096ull * 512 * 2);
  unsigned short* Wout_t  = (unsigned short*)alloc(2048ull * 2048 * 2);

  dim3 tblk(32, 8);

  cast_bf16<<<(4096 * 2048 / 4 + 255) / 256, 256, 0, stream>>>(x, xb, 4096 * 2048 / 4);
  transpose_cast<<<dim3(2048 / 32, 1024 / 32), tblk, 0, stream>>>(Wq_down, 2048, 1024, Wqdkv_t);
  transpose_cast<<<dim3(2048 / 32, 640 / 32), tblk, 0, stream>>>(Wkv_down, 2048, 576, Wqdkv_t + 1024ull * 2048);
  transpose_cast<<<dim3(1024 / 32, 3072 / 32), tblk, 0, stream>>>(Wq_up, 1024, 3072, Wqu_t);
  transpose_cast<<<dim3(512 / 32, 4096 / 32), tblk, 0, stream>>>(Wkv_up, 512, 4096, Wkvu_t);
  transpose_cast<<<dim3(2048 / 32, 2048 / 32), tblk, 0, stream>>>(Wout, 2048, 2048, Wout_t);

  // fused: [qdown | ckv] = xb @ [Wq_down | Wkv_down]  (M=4096, N=1664, K=2048)
  gemm_bt<unsigned short><<<dim3(1664 / 128, 32), 256, 0, stream>>>(
      xb, 2048, Wqdkv_t, 2048, qckvb, 1664, 2048);
  // qb = qdown @ Wq_up (N=3072, K=1024)
  gemm_bt<unsigned short><<<dim3(3072 / 128, 32), 256, 0, stream>>>(
      qckvb, 1664, Wqu_t, 1024, qb, 3072, 1024);
  // rope
  {
    int total = B_ * S_ * 17 * 32;
    rope_kernel<<<(total + 255) / 256, 256, 0, stream>>>(qb, qckvb, krb, position);
  }
  // kv_up with fused epilogue: knb (k_nope compact) + vtb (V transposed)
  gemm_kv<<<dim3(4096 / 128, 32), 256, 0, stream>>>(
      qckvb + 1024, 1664, Wkvu_t, 512, knb, vtb, 512);
  // attention -> aob (bf16), Q-tile 128
  attn_mfma<<<dim3(S_ / 128, HEADS_, B_), 256, 0, stream>>>(qb, knb, krb, vtb, aob);
  // out = aob @ Wout (fp32 out)
  gemm_bt<float><<<dim3(2048 / 128, 32), 256, 0, stream>>>(
      aob, 2048, Wout_t, 2048, out, 2048, 2048);
}

// Round 7
// 479.100 us; speedup vs baseline: 1.1302x; 1.1302x over previous
//
#include <hip/hip_runtime.h>
#include <math.h>

#define B_      2
#define S_      2048
#define HIDDEN_ 2048
#define HEADS_  16
#define QLORA_  1024
#define KVLORA_ 512
#define NOPE_   128
#define ROPE_   64
#define QHEAD_  192
#define VHEAD_  128

typedef __attribute__((ext_vector_type(8))) short bf16x8;
typedef __attribute__((ext_vector_type(4))) float f32x4;

#define AS1 __attribute__((address_space(1)))
#define AS3 __attribute__((address_space(3)))

static __device__ __forceinline__ unsigned short f2bf(float f) {
  unsigned u = __builtin_bit_cast(unsigned, f);
  u += 0x7fffu + ((u >> 16) & 1u);  // RTNE
  return (unsigned short)(u >> 16);
}
static __device__ __forceinline__ float b2f(unsigned short s) {
  unsigned u = ((unsigned)s) << 16;
  return __builtin_bit_cast(float, u);
}

// ---------------------------------------------------------------------------
// bf16 MFMA GEMM (m97 structure): C[M,N] = A[M,K] @ Bt[N,K]^T
// Tile 128x128, BK=32, 4 waves (2x2 of 64x64), 4x4 MFMA acc/wave.
// ---------------------------------------------------------------------------
template <typename TC>
__global__ __launch_bounds__(256) void gemm_bt(
    const unsigned short* __restrict__ A, int lda,   // [M][K] bf16
    const unsigned short* __restrict__ Bt, int ldb,  // [N][K] bf16
    TC* __restrict__ C, int ldc, int K) {
  __shared__ __align__(16) unsigned short As[128][32];
  __shared__ __align__(16) unsigned short Bs[128][32];

  const int tid = threadIdx.x;
  const int lane = tid & 63, wv = tid >> 6;
  const int m = lane & 15, quad = lane >> 4;
  const int wm = wv >> 1, wn = wv & 1;
  const int bm = blockIdx.y * 128, bn = blockIdx.x * 128;

  const int srow = lane >> 2;
  const int gchunk = (lane & 3) ^ ((lane >> 3) & 3);
  const int koff = (quad ^ ((m >> 1) & 3)) * 8;

  f32x4 acc[4][4] = {};

  const unsigned short* Ab = A + (size_t)bm * lda;
  const unsigned short* Bb = Bt + (size_t)bn * ldb;

  for (int k0 = 0; k0 < K; k0 += 32) {
    __syncthreads();
#pragma unroll
    for (int j = 0; j < 2; ++j) {
      const int t = wv * 2 + j;
      const int r = t * 16 + srow;
      __builtin_amdgcn_global_load_lds(
          (const AS1 unsigned int*)(Ab + (size_t)r * lda + k0 + gchunk * 8),
          (AS3 unsigned int*)(&As[0][0] + t * 512), 16, 0, 0);
      __builtin_amdgcn_global_load_lds(
          (const AS1 unsigned int*)(Bb + (size_t)r * ldb + k0 + gchunk * 8),
          (AS3 unsigned int*)(&Bs[0][0] + t * 512), 16, 0, 0);
    }
    __syncthreads();

    bf16x8 af[4], bfr[4];
#pragma unroll
    for (int mt = 0; mt < 4; ++mt)
      af[mt] = *(const bf16x8*)&As[wm * 64 + mt * 16 + m][koff];
#pragma unroll
    for (int nt = 0; nt < 4; ++nt)
      bfr[nt] = *(const bf16x8*)&Bs[wn * 64 + nt * 16 + m][koff];
#pragma unroll
    for (int mt = 0; mt < 4; ++mt)
#pragma unroll
      for (int nt = 0; nt < 4; ++nt)
        acc[mt][nt] = __builtin_amdgcn_mfma_f32_16x16x32_bf16(af[mt], bfr[nt], acc[mt][nt], 0, 0, 0);
  }

#pragma unroll
  for (int mt = 0; mt < 4; ++mt) {
#pragma unroll
    for (int reg = 0; reg < 4; ++reg) {
      const size_t row = (size_t)bm + wm * 64 + mt * 16 + quad * 4 + reg;
#pragma unroll
      for (int nt = 0; nt < 4; ++nt) {
        const size_t col = (size_t)bn + wn * 64 + nt * 16 + m;
        float v = acc[mt][nt][reg];
        if constexpr (sizeof(TC) == 4) {
          ((float*)C)[row * ldc + col] = v;
        } else {
          ((unsigned short*)C)[row * ldc + col] = f2bf(v);
        }
      }
    }
  }
}

// ---------------------------------------------------------------------------
// Weight transpose+cast: W fp32 [K][N] -> Wt bf16 [Npad][K] (zero-pad n>=N).
// ---------------------------------------------------------------------------
__global__ __launch_bounds__(256) void transpose_cast(
    const float* __restrict__ W, int K, int N,
    unsigned short* __restrict__ Wt) {
  __shared__ unsigned short t[32][33];
  const int k0 = blockIdx.x * 32, n0 = blockIdx.y * 32;
  const int tx = threadIdx.x, ty = threadIdx.y;
#pragma unroll
  for (int i = 0; i < 4; ++i) {
    int k = k0 + ty + i * 8, n = n0 + tx;
    float v = (n < N) ? W[(size_t)k * N + n] : 0.0f;
    t[ty + i * 8][tx] = f2bf(v);
  }
  __syncthreads();
#pragma unroll
  for (int i = 0; i < 4; ++i) {
    int n = ty + i * 8;
    Wt[(size_t)(n0 + n) * K + k0 + tx] = t[tx][n];
  }
}

__global__ void cast_bf16(const float* __restrict__ src,
                          unsigned short* __restrict__ dst, int n4) {
  int i = blockIdx.x * blockDim.x + threadIdx.x;
  if (i >= n4) return;
  float4 v = ((const float4*)src)[i];
  ushort4 o;
  o.x = f2bf(v.x); o.y = f2bf(v.y); o.z = f2bf(v.z); o.w = f2bf(v.w);
  ((ushort4*)dst)[i] = o;
}

// ---------------------------------------------------------------------------
// RoPE: qb bf16 in-place; k_rope from qckvb [bs][1664] cols 1536..1599 -> krb.
// ---------------------------------------------------------------------------
__global__ void rope_kernel(unsigned short* __restrict__ qb,
                            const unsigned short* __restrict__ qckvb,
                            unsigned short* __restrict__ krb,
                            const int* __restrict__ position) {
  int idx = blockIdx.x * blockDim.x + threadIdx.x;
  const int total = B_ * S_ * 17 * 32;
  if (idx >= total) return;
  int i = idx & 31;
  int u = idx >> 5;
  int h = u % 17;
  int bs = u / 17;
  int s = bs % S_;
  float pos = (float)position[s];
  float inv_freq = powf(10000.0f, -(float)i / 32.0f);
  float ang = pos * inv_freq;
  float c = cosf(ang), sn = sinf(ang);
  if (h < 16) {
    unsigned short* t = qb + (size_t)bs * 3072 + h * QHEAD_ + NOPE_;
    float t1 = b2f(t[i]), t2 = b2f(t[i + 32]);
    t[i]      = f2bf(t1 * c - t2 * sn);
    t[i + 32] = f2bf(t2 * c + t1 * sn);
  } else {
    const unsigned short* t = qckvb + (size_t)bs * 1664 + 1024 + 512;
    float t1 = b2f(t[i]), t2 = b2f(t[i + 32]);
    krb[(size_t)bs * 64 + i]      = f2bf(t1 * c - t2 * sn);
    krb[(size_t)bs * 64 + i + 32] = f2bf(t2 * c + t1 * sn);
  }
}

// ---------------------------------------------------------------------------
// V transpose: kvb bf16 [bs][h*256+128+d] -> vtb bf16 [(b*16+h)*128+d][s]
// ---------------------------------------------------------------------------
__global__ __launch_bounds__(256) void pack_vt(const unsigned short* __restrict__ kvb,
                                               unsigned short* __restrict__ vtb) {
  __shared__ unsigned short tile[32][33];
  int s0 = blockIdx.x * 32, d0 = blockIdx.y * 32, bh = blockIdx.z;
  int b = bh >> 4, h = bh & 15;
  int tx = threadIdx.x, ty = threadIdx.y;
#pragma unroll
  for (int i = 0; i < 4; ++i) {
    int sy = ty + i * 8;
    tile[sy][tx] = kvb[(size_t)(b * S_ + s0 + sy) * 4096 + h * 256 + 128 + d0 + tx];
  }
  __syncthreads();
#pragma unroll
  for (int i = 0; i < 4; ++i) {
    int d = ty + i * 8;
    vtb[((size_t)bh * 128 + d0 + d) * S_ + s0 + tx] = tile[tx][d];
  }
}

// ---------------------------------------------------------------------------
// Flash attention, bf16 MFMA, max-free softmax, Q-tile 128 (4 waves x 32 rows).
// R7: double-buffered K-tile 32 pipeline, ONE barrier per tile. Prefetch for
// tile t+1 (global_load_lds, XOR-swizzled) is issued right after the barrier
// and drained by the NEXT barrier -- a full tile of QK+exp+PV hides the load
// latency (true async prefetch; breaks the R6 stage->drain->compute chain).
// LDS 50.2 KB -> 2 blocks/CU. Grid (S/128, HEADS, B).
// ---------------------------------------------------------------------------
__global__ __launch_bounds__(256) void attn_mfma(
    const unsigned short* __restrict__ qb,   // [bs][3072] bf16, rope applied
    const unsigned short* __restrict__ kvb,  // [bs][4096] bf16 (k_nope|v per head)
    const unsigned short* __restrict__ krb,  // [bs][64] bf16 roped k_rope
    const unsigned short* __restrict__ vtb,  // [(b*16+h)*128+d][2048] bf16
    unsigned short* __restrict__ aob) {      // [bs][2048] bf16
  __shared__ __align__(16) unsigned short Ksn[2][32 * 128];  // key*128 + slot*8
  __shared__ __align__(16) unsigned short Ksr[2][32 * 64];   // key*64  + slot*8
  __shared__ __align__(16) unsigned short Vt[2][128 * 32];   // d*32    + slot*8
  __shared__ __align__(16) unsigned short Ps[4][32][40];     // per-wave P

  const int qt = blockIdx.x, h = blockIdx.y, b = blockIdx.z;
  const int tid = threadIdx.x;
  const int lane = tid & 63, wv = tid >> 6;
  const int m = lane & 15, quad = lane >> 4;
  const int bS = b * S_;
  const int bh = b * 16 + h;
  const float scale = 0.072168783649f;  // 1/sqrt(192)

  // Q A-fragments for 2 M-tiles (32 q-rows per wave), loaded once
  bf16x8 qf[2][6];
#pragma unroll
  for (int mt2 = 0; mt2 < 2; ++mt2) {
    const unsigned short* qptr =
        qb + (size_t)(bS + qt * 128 + wv * 32 + mt2 * 16 + m) * 3072 + h * QHEAD_ + quad * 8;
#pragma unroll
    for (int c = 0; c < 6; ++c) qf[mt2][c] = *(const bf16x8*)(qptr + c * 32);
  }

  // staging lane constants
  const int kn_keyoff = lane >> 4;                       // 0..3
  const int kr_keyoff = lane >> 3;                       // 0..7
  const int vt_doff   = lane >> 2;                       // 0..15
  const int kr_cc = (lane & 7) ^ (lane >> 3);
  const int vt_cc = (lane & 3) ^ ((lane >> 2) & 3);

  auto stage = [&](int kt, int bi) {
    // K-nope: 32 keys x 256B; 8 instrs; instr i covers keys i*4..i*4+3
#pragma unroll
    for (int j = 0; j < 2; ++j) {
      int i = wv * 2 + j;
      int key = i * 4 + kn_keyoff;
      int cc = (lane & 15) ^ (key & 15);
      __builtin_amdgcn_global_load_lds(
          (const AS1 unsigned int*)(kvb + (size_t)(bS + kt + key) * 4096 + h * 256 + cc * 8),
          (AS3 unsigned int*)(&Ksn[bi][i * 512]), 16, 0, 0);
    }
    // K-rope: 32 keys x 128B; 4 instrs; instr i covers keys i*8..i*8+7
    {
      int i = wv;
      int key = i * 8 + kr_keyoff;
      __builtin_amdgcn_global_load_lds(
          (const AS1 unsigned int*)(krb + (size_t)(bS + kt + key) * 64 + kr_cc * 8),
          (AS3 unsigned int*)(&Ksr[bi][i * 512]), 16, 0, 0);
    }
    // Vt: 128 d x 64B; 8 instrs; instr i covers d i*16..i*16+15
#pragma unroll
    for (int j = 0; j < 2; ++j) {
      int i = wv * 2 + j;
      int d = i * 16 + vt_doff;
      __builtin_amdgcn_global_load_lds(
          (const AS1 unsigned int*)(vtb + ((size_t)bh * 128 + d) * 2048 + kt + vt_cc * 8),
          (AS3 unsigned int*)(&Vt[bi][i * 512]), 16, 0, 0);
    }
  };

  const bf16x8 vone = {0x3F80, 0x3F80, 0x3F80, 0x3F80, 0x3F80, 0x3F80, 0x3F80, 0x3F80};

  f32x4 o[2][8] = {};
  f32x4 o9[2] = {};

  stage(0, 0);  // prologue prefetch

  const int NT = S_ / 32;  // 64 tiles
  for (int t = 0; t < NT; ++t) {
    const int bi = t & 1;
    __syncthreads();  // drains vmcnt(0): buf[bi] complete; all waves done reading buf[bi] from 2 iters ago
    if (t + 1 < NT) stage((t + 1) * 32, bi ^ 1);

    // --- QK^T (32 keys): each K-frag read feeds both M-tiles ---
    f32x4 sc[2][2] = {};
#pragma unroll
    for (int c = 0; c < 4; ++c) {  // nope chunks
#pragma unroll
      for (int f = 0; f < 2; ++f) {
        int slot = (c * 4 + quad) ^ m;
        bf16x8 kf = *(const bf16x8*)&Ksn[bi][(f * 16 + m) * 128 + slot * 8];
        sc[0][f] = __builtin_amdgcn_mfma_f32_16x16x32_bf16(qf[0][c], kf, sc[0][f], 0, 0, 0);
        sc[1][f] = __builtin_amdgcn_mfma_f32_16x16x32_bf16(qf[1][c], kf, sc[1][f], 0, 0, 0);
      }
    }
#pragma unroll
    for (int c2 = 0; c2 < 2; ++c2) {  // rope chunks
#pragma unroll
      for (int f = 0; f < 2; ++f) {
        int slot = (c2 * 4 + quad) ^ (m & 7);
        bf16x8 kf = *(const bf16x8*)&Ksr[bi][(f * 16 + m) * 64 + slot * 8];
        sc[0][f] = __builtin_amdgcn_mfma_f32_16x16x32_bf16(qf[0][4 + c2], kf, sc[0][f], 0, 0, 0);
        sc[1][f] = __builtin_amdgcn_mfma_f32_16x16x32_bf16(qf[1][4 + c2], kf, sc[1][f], 0, 0, 0);
      }
    }

    // --- exp -> Ps (per-wave LDS, C-layout scatter) ---
#pragma unroll
    for (int mt2 = 0; mt2 < 2; ++mt2)
#pragma unroll
      for (int f = 0; f < 2; ++f)
#pragma unroll
        for (int r = 0; r < 4; ++r)
          Ps[wv][mt2 * 16 + quad * 4 + r][f * 16 + m] = f2bf(__expf(sc[mt2][f][r] * scale));

    // --- PV (one K=32 MFMA chunk): each V-frag read feeds both M-tiles ---
    bf16x8 pf0 = *(const bf16x8*)&Ps[wv][m][quad * 8];
    bf16x8 pf1 = *(const bf16x8*)&Ps[wv][16 + m][quad * 8];
    const int vslot = quad ^ (m & 3);
#pragma unroll
    for (int nt = 0; nt < 8; ++nt) {
      bf16x8 vf = *(const bf16x8*)&Vt[bi][(nt * 16 + m) * 32 + vslot * 8];
      o[0][nt] = __builtin_amdgcn_mfma_f32_16x16x32_bf16(pf0, vf, o[0][nt], 0, 0, 0);
      o[1][nt] = __builtin_amdgcn_mfma_f32_16x16x32_bf16(pf1, vf, o[1][nt], 0, 0, 0);
    }
    o9[0] = __builtin_amdgcn_mfma_f32_16x16x32_bf16(pf0, vone, o9[0], 0, 0, 0);
    o9[1] = __builtin_amdgcn_mfma_f32_16x16x32_bf16(pf1, vone, o9[1], 0, 0, 0);
  }

#pragma unroll
  for (int mt2 = 0; mt2 < 2; ++mt2) {
#pragma unroll
    for (int r = 0; r < 4; ++r) {
      float inv = 1.0f / o9[mt2][r];
      size_t row = (size_t)(bS + qt * 128 + wv * 32 + mt2 * 16 + quad * 4 + r);
#pragma unroll
      for (int nt = 0; nt < 8; ++nt)
        aob[row * 2048 + h * VHEAD_ + nt * 16 + m] = f2bf(o[mt2][nt][r] * inv);
    }
  }
}

// ---------------------------------------------------------------------------
extern "C" void kernel_launch(void* const* d_in, const int* in_sizes, int n_in,
                              void* d_out, int out_size, void* d_ws, size_t ws_size,
                              hipStream_t stream) {
  const float* x        = (const float*)d_in[0];
  const int*   position = (const int*)d_in[1];
  const float* Wq_down  = (const float*)d_in[2];  // [2048,1024]
  const float* Wq_up    = (const float*)d_in[3];  // [1024,3072]
  const float* Wkv_down = (const float*)d_in[4];  // [2048,576]
  const float* Wkv_up   = (const float*)d_in[5];  // [512,4096]
  const float* Wout     = (const float*)d_in[6];  // [2048,2048]
  float* out = (float*)d_out;

  char* w = (char*)d_ws;
  size_t off = 0;
  auto alloc = [&](size_t bytes) { char* p = w + off; off += (bytes + 255) & ~size_t(255); return p; };
  unsigned short* xb      = (unsigned short*)alloc(4096ull * 2048 * 2);
  unsigned short* qckvb   = (unsigned short*)alloc(4096ull * 1664 * 2);  // [qdown | ckv(640)]
  unsigned short* qb      = (unsigned short*)alloc(4096ull * 3072 * 2);
  unsigned short* kvb     = (unsigned short*)alloc(4096ull * 4096 * 2);
  unsigned short* vtb     = (unsigned short*)alloc(32ull * 128 * 2048 * 2);
  unsigned short* krb     = (unsigned short*)alloc(4096ull * 64 * 2);
  unsigned short* aob     = (unsigned short*)alloc(4096ull * 2048 * 2);
  unsigned short* Wqdkv_t = (unsigned short*)alloc(1664ull * 2048 * 2);  // [Wqd^T | Wkvd^T(640)]
  unsigned short* Wqu_t   = (unsigned short*)alloc(3072ull * 1024 * 2);
  unsigned short* Wkvu_t  = (unsigned short*)alloc(4096ull * 512 * 2);
  unsigned short* Wout_t  = (unsigned short*)alloc(2048ull * 2048 * 2);

  dim3 tblk(32, 8);

  cast_bf16<<<(4096 * 2048 / 4 + 255) / 256, 256, 0, stream>>>(x, xb, 4096 * 2048 / 4);
  transpose_cast<<<dim3(2048 / 32, 1024 / 32), tblk, 0, stream>>>(Wq_down, 2048, 1024, Wqdkv_t);
  transpose_cast<<<dim3(2048 / 32, 640 / 32), tblk, 0, stream>>>(Wkv_down, 2048, 576, Wqdkv_t + 1024ull * 2048);
  transpose_cast<<<dim3(1024 / 32, 3072 / 32), tblk, 0, stream>>>(Wq_up, 1024, 3072, Wqu_t);
  transpose_cast<<<dim3(512 / 32, 4096 / 32), tblk, 0, stream>>>(Wkv_up, 512, 4096, Wkvu_t);
  transpose_cast<<<dim3(2048 / 32, 2048 / 32), tblk, 0, stream>>>(Wout, 2048, 2048, Wout_t);

  // fused: [qdown | ckv] = xb @ [Wq_down | Wkv_down]  (M=4096, N=1664, K=2048)
  gemm_bt<unsigned short><<<dim3(1664 / 128, 32), 256, 0, stream>>>(
      xb, 2048, Wqdkv_t, 2048, qckvb, 1664, 2048);
  // qb = qdown @ Wq_up (N=3072, K=1024)
  gemm_bt<unsigned short><<<dim3(3072 / 128, 32), 256, 0, stream>>>(
      qckvb, 1664, Wqu_t, 1024, qb, 3072, 1024);
  // rope
  {
    int total = B_ * S_ * 17 * 32;
    rope_kernel<<<(total + 255) / 256, 256, 0, stream>>>(qb, qckvb, krb, position);
  }
  // kvb = ckv[:, :512] @ Wkv_up (N=4096, K=512)
  gemm_bt<unsigned short><<<dim3(4096 / 128, 32), 256, 0, stream>>>(
      qckvb + 1024, 1664, Wkvu_t, 512, kvb, 4096, 512);
  // vtb = transpose(V) per head
  pack_vt<<<dim3(S_ / 32, 128 / 32, B_ * HEADS_), tblk, 0, stream>>>(kvb, vtb);
  // attention -> aob (bf16), Q-tile 128, double-buffered pipeline
  attn_mfma<<<dim3(S_ / 128, HEADS_, B_), 256, 0, stream>>>(qb, kvb, krb, vtb, aob);
  // out = aob @ Wout (fp32 out)
  gemm_bt<float><<<dim3(2048 / 128, 32), 256, 0, stream>>>(
      aob, 2048, Wout_t, 2048, out, 2048, 2048);
}